// Round 12
// baseline (410.552 us; speedup 1.0000x reference)
//
#include <hip/hip_runtime.h>
#include <hip/hip_bf16.h>

#define B_    16
#define C_    96
#define H_    224
#define W_    224
#define COUT_ 96
#define GH_   14
#define GW_   14
#define P_    196          // GH_*GW_
#define HW_   (H_*W_)      // 50176
#define NCH_  12           // 8-channel chunks

#define AS1 __attribute__((address_space(1)))
#define AS3 __attribute__((address_space(3)))

typedef __attribute__((ext_vector_type(8))) unsigned short ushort8;
typedef __attribute__((ext_vector_type(8))) short        short8;   // MFMA bf16x8 operand
typedef __attribute__((ext_vector_type(4))) float        f32x4;

__device__ __forceinline__ unsigned short f2bf(float f) {
    union { __hip_bfloat16 h; unsigned short u; } cv;
    cv.h = __float2bfloat16(f);
    return cv.u;
}

// ---------------------------------------------------------------------------
// Kernel 0: of (COUT,C,3,3) f32 -> ofb[tap][cout][c] bf16; zero-page for OOB.
// ---------------------------------------------------------------------------
__global__ __launch_bounds__(256) void prep_ofb(const float* __restrict__ of,
                                                unsigned short* __restrict__ ofb,
                                                unsigned short* __restrict__ zp) {
    if (blockIdx.x == 0 && threadIdx.x < 128) zp[threadIdx.x] = 0;
    int idx = blockIdx.x * 256 + threadIdx.x;      // 9*96*96 = 82944
    if (idx < 9 * 96 * 96) {
        int tap = idx / (96 * 96);
        int r   = idx % (96 * 96);
        int cout = r / 96, c = r % 96;
        ofb[idx] = f2bf(of[((size_t)cout * 96 + c) * 9 + tap]);
    }
}

// ---------------------------------------------------------------------------
// Kernel 1: per-patch depthwise 3x3 (patch-local zero padding).
// x: (B,C,H,W) f32 -> sa: (B, 12, H, W, 8) bf16  (8-ch chunk planes).
// (R5-proven: ~107 us, near traffic floor. Unchanged.)
// ---------------------------------------------------------------------------
__global__ __launch_bounds__(256) void sa_kernel(const float* __restrict__ x,
                                                 const float* __restrict__ pf,
                                                 unsigned short* __restrict__ sa) {
    int bid   = blockIdx.x;
    int patch = bid % P_;
    int b     = bid / P_;
    int gh = patch / GW_, gw = patch % GW_;
    int t  = threadIdx.x;
    int py = t >> 4, px = t & 15;
    int y  = gh * 16 + py, xx = gw * 16 + px;

    __shared__ float xs[2][8][256];    // 16 KB double-buffered x slice

    const float* xp0 = x + (size_t)b * C_ * HW_ + (size_t)y * W_ + xx;

    float lf[8];
    #pragma unroll
    for (int ch = 0; ch < 8; ++ch) lf[ch] = xp0[(size_t)ch * HW_];

    for (int cc = 0; cc < NCH_; ++cc) {
        int buf = cc & 1;
        #pragma unroll
        for (int ch = 0; ch < 8; ++ch) xs[buf][ch][t] = lf[ch];
        __syncthreads();
        if (cc < NCH_ - 1) {
            #pragma unroll
            for (int ch = 0; ch < 8; ++ch)
                lf[ch] = xp0[(size_t)((cc + 1) * 8 + ch) * HW_];
        }

        ushort8 v;
        #pragma unroll
        for (int ch = 0; ch < 8; ++ch) {
            const float* wgt = pf + ((size_t)(cc * 8 + ch) * P_ + patch) * 9;  // uniform -> s_load
            float a = 0.f;
            #pragma unroll
            for (int dy = -1; dy <= 1; ++dy) {
                int yy = py + dy;
                if ((unsigned)yy < 16u) {
                    #pragma unroll
                    for (int dx = -1; dx <= 1; ++dx) {
                        int xq = px + dx;
                        if ((unsigned)xq < 16u)
                            a = fmaf(xs[buf][ch][yy * 16 + xq],
                                     wgt[(dy + 1) * 3 + (dx + 1)], a);
                    }
                }
            }
            v[ch] = f2bf(a);
        }
        *(ushort8*)&sa[(((size_t)(b * NCH_ + cc) * H_ + y) * W_ + xx) * 8] = v;
    }
}

// ---------------------------------------------------------------------------
// Kernel 2: implicit-GEMM MFMA conv + exact GELU, half-patch blocks.
// R12: STAGE-ONCE structure (the measured-best R2 shape, modernized):
//   - full 12-plane A halo (10x18x96 bf16 = 34.6 KB + trash = 36.9 KB LDS)
//     staged via global_load_lds in ONE burst, ONE barrier;
//   - after the barrier the vmcnt queue is EMPTY: the 27 (g,tap) MFMA steps
//     see only bf global loads -> compiler prefetches taps ahead freely
//     (R5..R11 regression: in-loop STAGE poisoned every bf wait with the
//      next group's HBM DMA, serializing all blocks equally -> occupancy-
//      insensitive ~300 us floor);
//   - 256 thr / 4 waves (2M x 2N), acc[4][3]=48 AGPR, launch_bounds(256,4):
//     R11 measured 72 arch regs -> fits 128-unified budget, 4 blocks/CU.
// ---------------------------------------------------------------------------
__global__ __launch_bounds__(256, 4) void conv2_mfma(const unsigned short* __restrict__ sa,
                                                     const unsigned short* __restrict__ ofb,
                                                     const unsigned short* __restrict__ zp,
                                                     float* __restrict__ out) {
    // XCD-aware swizzle (6272 % 8 == 0 -> bijective); logical order keeps
    // same-patch halves adjacent for L2 halo sharing.
    int bid0 = blockIdx.x;
    int bid  = (bid0 % 8) * (6272 / 8) + bid0 / 8;
    int half = bid & 1;
    int pid  = bid >> 1;
    int patch = pid % P_;
    int b     = pid / P_;
    int gh = patch / GW_, gw = patch % GW_;
    int y0 = gh * 16 + half * 8, x0 = gw * 16;   // 8x16 output region

    int t = threadIdx.x;
    int w = t >> 6, l = t & 63;
    int wm = w & 1, wn = w >> 1;            // 2 M-waves x 2 N-waves
    int mrow = l & 15, kgrp = l >> 4;

    __shared__ ushort8 at8[2304];           // 12 planes x 180 px + 144 trash = 36864 B

    // ---- single staging burst: whole 10x18 halo, all 12 chunk-planes ----
    #pragma unroll
    for (int i = 0; i < 9; ++i) {
        int v = t + i * 256;                // 0..2303; [0,2160) real
        const unsigned short* src = zp;
        if (v < 2160) {
            int ccl = v / 180, hpx = v - ccl * 180;
            int gy = y0 - 1 + hpx / 18, gx = x0 - 1 + hpx % 18;
            if ((unsigned)gy < (unsigned)H_ && (unsigned)gx < (unsigned)W_)
                src = &sa[(((size_t)(b * NCH_ + ccl) * H_ + gy) * W_ + gx) * 8];
        }
        __builtin_amdgcn_global_load_lds((const AS1 unsigned int*)src,
                                         (AS3 unsigned int*)&at8[v], 16, 0, 0);
    }

    f32x4 acc[4][3];
    #pragma unroll
    for (int mi = 0; mi < 4; ++mi)
        #pragma unroll
        for (int ni = 0; ni < 3; ++ni)
            acc[mi][ni] = (f32x4)0.f;

    __syncthreads();                        // drain DMA; tile visible; queue EMPTY

    const unsigned short* at = (const unsigned short*)at8;

    // ---- pure compute: 3 groups x 9 taps, only bf loads touch vmcnt ----
    #pragma unroll 1
    for (int g = 0; g < 3; ++g) {
        #pragma unroll                      // 108-MFMA window per group
        for (int tap = 0; tap < 9; ++tap) {
            int ky = tap / 3, kx = tap % 3;
            const unsigned short* bofs = ofb + tap * (96 * 96) + (wn * 48) * 96
                                         + g * 32 + kgrp * 8;
            short8 bf[3];
            #pragma unroll
            for (int ni = 0; ni < 3; ++ni)
                bf[ni] = *(const short8*)&bofs[(ni * 16 + mrow) * 96];
            #pragma unroll
            for (int mi = 0; mi < 4; ++mi) {
                short8 af = *(const short8*)&at[((g * 4 + kgrp) * 180
                                                + (wm * 4 + mi + ky) * 18
                                                + kx + mrow) * 8];
                #pragma unroll
                for (int ni = 0; ni < 3; ++ni)
                    acc[mi][ni] = __builtin_amdgcn_mfma_f32_16x16x32_bf16(
                        af, bf[ni], acc[mi][ni], 0, 0, 0);
            }
        }
    }

    // ---- epilogue: exact GELU + f32x4 stores ----
    #pragma unroll
    for (int mi = 0; mi < 4; ++mi) {
        int gy = y0 + wm * 4 + mi;
        #pragma unroll
        for (int ni = 0; ni < 3; ++ni) {
            int cout = wn * 48 + ni * 16 + mrow;
            f32x4 gv;
            #pragma unroll
            for (int j = 0; j < 4; ++j) {
                float vv = acc[mi][ni][j];
                gv[j] = 0.5f * vv * (1.0f + erff(vv * 0.70710678118f));
            }
            *(f32x4*)&out[((size_t)b * COUT_ + cout) * HW_ + (size_t)gy * W_ +
                          x0 + kgrp * 4] = gv;
        }
    }
}

extern "C" void kernel_launch(void* const* d_in, const int* in_sizes, int n_in,
                              void* d_out, int out_size, void* d_ws, size_t ws_size,
                              hipStream_t stream) {
    const float* x  = (const float*)d_in[0];
    const float* pf = (const float*)d_in[1];
    const float* of = (const float*)d_in[2];
    float* out = (float*)d_out;

    unsigned short* sa  = (unsigned short*)d_ws;                       // 154,140,672 B
    unsigned short* ofb = (unsigned short*)((char*)d_ws + 154140672);  // + 165,888 B
    unsigned short* zp  = (unsigned short*)((char*)d_ws + 154306560);  // + 256 B zero-page

    prep_ofb<<<324, 256, 0, stream>>>(of, ofb, zp);
    sa_kernel<<<B_ * P_, 256, 0, stream>>>(x, pf, sa);
    conv2_mfma<<<B_ * P_ * 2, 256, 0, stream>>>(sa, ofb, zp, out);
}

// Round 13
// 404.432 us; speedup vs baseline: 1.0151x; 1.0151x over previous
//
#include <hip/hip_runtime.h>
#include <hip/hip_bf16.h>

#define B_    16
#define C_    96
#define H_    224
#define W_    224
#define COUT_ 96
#define GH_   14
#define GW_   14
#define P_    196          // GH_*GW_
#define HW_   (H_*W_)      // 50176
#define NCH_  12           // 8-channel chunks

#define AS1 __attribute__((address_space(1)))
#define AS3 __attribute__((address_space(3)))

typedef __attribute__((ext_vector_type(8))) unsigned short ushort8;
typedef __attribute__((ext_vector_type(8))) short        short8;   // MFMA bf16x8 operand
typedef __attribute__((ext_vector_type(4))) float        f32x4;

__device__ __forceinline__ unsigned short f2bf(float f) {
    union { __hip_bfloat16 h; unsigned short u; } cv;
    cv.h = __float2bfloat16(f);
    return cv.u;
}

// ---------------------------------------------------------------------------
// Kernel 0: of (COUT,C,3,3) f32 -> ofb[tap][cout][c] bf16; zero-page for OOB.
// ---------------------------------------------------------------------------
__global__ __launch_bounds__(256) void prep_ofb(const float* __restrict__ of,
                                                unsigned short* __restrict__ ofb,
                                                unsigned short* __restrict__ zp) {
    if (blockIdx.x == 0 && threadIdx.x < 128) zp[threadIdx.x] = 0;
    int idx = blockIdx.x * 256 + threadIdx.x;      // 9*96*96 = 82944
    if (idx < 9 * 96 * 96) {
        int tap = idx / (96 * 96);
        int r   = idx % (96 * 96);
        int cout = r / 96, c = r % 96;
        ofb[idx] = f2bf(of[((size_t)cout * 96 + c) * 9 + tap]);
    }
}

// ---------------------------------------------------------------------------
// Kernel 1: per-patch depthwise 3x3 (patch-local zero padding).
// x: (B,C,H,W) f32 -> sa: (B, 12, H, W, 8) bf16  (8-ch chunk planes).
// (R5-proven: ~107 us, near traffic floor. Unchanged.)
// ---------------------------------------------------------------------------
__global__ __launch_bounds__(256) void sa_kernel(const float* __restrict__ x,
                                                 const float* __restrict__ pf,
                                                 unsigned short* __restrict__ sa) {
    int bid   = blockIdx.x;
    int patch = bid % P_;
    int b     = bid / P_;
    int gh = patch / GW_, gw = patch % GW_;
    int t  = threadIdx.x;
    int py = t >> 4, px = t & 15;
    int y  = gh * 16 + py, xx = gw * 16 + px;

    __shared__ float xs[2][8][256];    // 16 KB double-buffered x slice

    const float* xp0 = x + (size_t)b * C_ * HW_ + (size_t)y * W_ + xx;

    float lf[8];
    #pragma unroll
    for (int ch = 0; ch < 8; ++ch) lf[ch] = xp0[(size_t)ch * HW_];

    for (int cc = 0; cc < NCH_; ++cc) {
        int buf = cc & 1;
        #pragma unroll
        for (int ch = 0; ch < 8; ++ch) xs[buf][ch][t] = lf[ch];
        __syncthreads();
        if (cc < NCH_ - 1) {
            #pragma unroll
            for (int ch = 0; ch < 8; ++ch)
                lf[ch] = xp0[(size_t)((cc + 1) * 8 + ch) * HW_];
        }

        ushort8 v;
        #pragma unroll
        for (int ch = 0; ch < 8; ++ch) {
            const float* wgt = pf + ((size_t)(cc * 8 + ch) * P_ + patch) * 9;  // uniform -> s_load
            float a = 0.f;
            #pragma unroll
            for (int dy = -1; dy <= 1; ++dy) {
                int yy = py + dy;
                if ((unsigned)yy < 16u) {
                    #pragma unroll
                    for (int dx = -1; dx <= 1; ++dx) {
                        int xq = px + dx;
                        if ((unsigned)xq < 16u)
                            a = fmaf(xs[buf][ch][yy * 16 + xq],
                                     wgt[(dy + 1) * 3 + (dx + 1)], a);
                    }
                }
            }
            v[ch] = f2bf(a);
        }
        *(ushort8*)&sa[(((size_t)(b * NCH_ + cc) * H_ + y) * W_ + xx) * 8] = v;
    }
}

// ---------------------------------------------------------------------------
// Kernel 2: implicit-GEMM MFMA conv + exact GELU, FULL-PATCH blocks.
// R13 = R2's high-reuse wave shape + stage-once DMA + register bf pipeline:
//   - block = 16x16 px x 96 couts, 4 all-M waves; wave = 64 px x 96 couts,
//     acc[4][6] = 96 acc regs; 4 af-reads feed 24 MFMAs (2x LDS reuse of
//     R5..R12), 6 bf-loads feed 24 MFMAs;
//   - 18x18x12-plane halo (62.2 KB + trash = 64 KB) staged ONCE via
//     global_load_lds, one barrier, vmcnt queue empty in the loop;
//   - bf DOUBLE-BUFFERED IN REGISTERS (bfA/bfB, 27 steps fully unrolled so
//     buffer choice is compile-time): step T+1's 6 loads issue BEFORE step
//     T's MFMAs -> compiler emits counted vmcnt, L2 latency hidden under
//     ~116 cyc of MFMA issue (the R6..R12 limiter: VGPR_Count=60 meant NO
//     pipeline existed; launch_bounds(256,2) gives ~160 arch regs).
// ---------------------------------------------------------------------------
__global__ __launch_bounds__(256, 2) void conv2_mfma(const unsigned short* __restrict__ sa,
                                                     const unsigned short* __restrict__ ofb,
                                                     const unsigned short* __restrict__ zp,
                                                     float* __restrict__ out) {
    // XCD-aware swizzle (3136 % 8 == 0 -> bijective)
    int bid0 = blockIdx.x;
    int bid  = (bid0 % 8) * (3136 / 8) + bid0 / 8;
    int patch = bid % P_;
    int b     = bid / P_;
    int gh = patch / GW_, gw = patch % GW_;
    int y0 = gh * 16, x0 = gw * 16;

    int t = threadIdx.x;
    int w = t >> 6, l = t & 63;             // 4 all-M waves
    int mrow = l & 15, kgrp = l >> 4;

    __shared__ ushort8 at8[4096];           // 3888 tile + 208 trash = 65536 B

    // ---- single staging burst: whole 18x18 halo, all 12 chunk-planes ----
    #pragma unroll
    for (int i = 0; i < 16; ++i) {
        int v = t + i * 256;                // 0..4095; [0,3888) real
        const unsigned short* src = zp;
        if (v < 3888) {
            int ccl = v / 324, hpx = v - ccl * 324;
            int gy = y0 - 1 + hpx / 18, gx = x0 - 1 + hpx % 18;
            if ((unsigned)gy < (unsigned)H_ && (unsigned)gx < (unsigned)W_)
                src = &sa[(((size_t)(b * NCH_ + ccl) * H_ + gy) * W_ + gx) * 8];
        }
        __builtin_amdgcn_global_load_lds((const AS1 unsigned int*)src,
                                         (AS3 unsigned int*)&at8[v], 16, 0, 0);
    }

    f32x4 acc[4][6];
    #pragma unroll
    for (int mi = 0; mi < 4; ++mi)
        #pragma unroll
        for (int ni = 0; ni < 6; ++ni)
            acc[mi][ni] = (f32x4)0.f;

    __syncthreads();                        // drain DMA; tile visible; queue EMPTY

    const unsigned short* at = (const unsigned short*)at8;

    // bf fetch for step T = g*9 + tap: ofb[tap][ni*16+mrow][g*32+kgrp*8]
    short8 bfA[6], bfB[6];
    auto LOADBF = [&](short8* dst, int T) {
        int g = T / 9, tap = T % 9;
        const unsigned short* bofs = ofb + tap * (96 * 96) + g * 32 + kgrp * 8;
        #pragma unroll
        for (int ni = 0; ni < 6; ++ni)
            dst[ni] = *(const short8*)&bofs[(ni * 16 + mrow) * 96];
    };

    LOADBF(bfA, 0);
    #pragma unroll                          // FULL unroll: T compile-time ->
    for (int T = 0; T < 27; ++T) {          // bfA/bfB selection is static
        short8* cur = (T & 1) ? bfB : bfA;
        short8* nxt = (T & 1) ? bfA : bfB;
        if (T + 1 < 27) LOADBF(nxt, T + 1); // issue-early: next step in flight

        int g = T / 9, tap = T % 9;
        int ky = tap / 3, kx = tap % 3;
        #pragma unroll
        for (int mi = 0; mi < 4; ++mi) {
            short8 af = *(const short8*)&at[((g * 4 + kgrp) * 324
                                            + (w * 4 + mi + ky) * 18
                                            + kx + mrow) * 8];
            #pragma unroll
            for (int ni = 0; ni < 6; ++ni)
                acc[mi][ni] = __builtin_amdgcn_mfma_f32_16x16x32_bf16(
                    af, cur[ni], acc[mi][ni], 0, 0, 0);
        }
    }

    // ---- epilogue: exact GELU + f32x4 stores ----
    #pragma unroll
    for (int mi = 0; mi < 4; ++mi) {
        int gy = y0 + w * 4 + mi;
        #pragma unroll
        for (int ni = 0; ni < 6; ++ni) {
            int cout = ni * 16 + mrow;
            f32x4 gv;
            #pragma unroll
            for (int j = 0; j < 4; ++j) {
                float vv = acc[mi][ni][j];
                gv[j] = 0.5f * vv * (1.0f + erff(vv * 0.70710678118f));
            }
            *(f32x4*)&out[((size_t)b * COUT_ + cout) * HW_ + (size_t)gy * W_ +
                          x0 + kgrp * 4] = gv;
        }
    }
}

extern "C" void kernel_launch(void* const* d_in, const int* in_sizes, int n_in,
                              void* d_out, int out_size, void* d_ws, size_t ws_size,
                              hipStream_t stream) {
    const float* x  = (const float*)d_in[0];
    const float* pf = (const float*)d_in[1];
    const float* of = (const float*)d_in[2];
    float* out = (float*)d_out;

    unsigned short* sa  = (unsigned short*)d_ws;                       // 154,140,672 B
    unsigned short* ofb = (unsigned short*)((char*)d_ws + 154140672);  // + 165,888 B
    unsigned short* zp  = (unsigned short*)((char*)d_ws + 154306560);  // + 256 B zero-page

    prep_ofb<<<324, 256, 0, stream>>>(of, ofb, zp);
    sa_kernel<<<B_ * P_, 256, 0, stream>>>(x, pf, sa);
    conv2_mfma<<<B_ * P_, 256, 0, stream>>>(sa, ofb, zp, out);
}